// Round 1
// baseline (5114.044 us; speedup 1.0000x reference)
//
#include <hip/hip_runtime.h>
#include <math.h>

#define NPTS  524288
#define NRAYS 4096
#define ACT_SHIFT_F (-2.1972245773362196f)   // log(1/(1-0.1) - 1)
#define INTERVAL_F  0.5f

// ---------------- register-resident GEMV helpers (fully unrolled) ----------

template<int OUT>
__device__ __forceinline__ void bias_init(float (&acc)[OUT], const float* __restrict__ B) {
#pragma unroll
    for (int j = 0; j < OUT; ++j) acc[j] = B[j];
}

template<int IN, int OUT>
__device__ __forceinline__ void gemv_acc(const float (&hin)[IN], float (&acc)[OUT],
                                         const float* __restrict__ W) {
#pragma unroll
    for (int i = 0; i < IN; ++i) {
        const float v = hin[i];
#pragma unroll
        for (int j = 0; j < OUT; ++j) acc[j] = fmaf(v, W[i * OUT + j], acc[j]);
    }
}

template<int OUT>
__device__ __forceinline__ void relu_(float (&acc)[OUT]) {
#pragma unroll
    for (int j = 0; j < OUT; ++j) acc[j] = fmaxf(acc[j], 0.0f);
}

// ---------------- kernel 1: per-point MLP -> rgb (P,3) into workspace ------

extern "C" __global__ void __launch_bounds__(256)
mlp_points(const float* __restrict__ coor,
           const float* __restrict__ view,
           const int*   __restrict__ ray_id,
           const float* __restrict__ wb0, const float* __restrict__ bb0,
           const float* __restrict__ wb1, const float* __restrict__ bb1,
           const float* __restrict__ wb2, const float* __restrict__ bb2,
           const float* __restrict__ wa0, const float* __restrict__ ba0,
           const float* __restrict__ wa1, const float* __restrict__ ba1,
           const float* __restrict__ wa2, const float* __restrict__ ba2,
           const float* __restrict__ wlat, const float* __restrict__ blat,
           const float* __restrict__ wview, const float* __restrict__ bview,
           const float* __restrict__ wc0, const float* __restrict__ bc0,
           const float* __restrict__ wc1, const float* __restrict__ bc1,
           float* __restrict__ rgb_out)
{
    const int p = blockIdx.x * 256 + threadIdx.x;

    const float x = coor[3 * p + 0];
    const float y = coor[3 * p + 1];
    const float z = coor[3 * p + 2];

    // sin_emb(coor, 5): [x, sin(2^f x), cos(2^f x)] per-freq blocks of 6
    float emb[33];
    emb[0] = x; emb[1] = y; emb[2] = z;
#pragma unroll
    for (int f = 0; f < 5; ++f) {
        const float fac = (float)(1 << f);
        float sx, cx, sy, cy, sz, cz;
        sincosf(fac * x, &sx, &cx);
        sincosf(fac * y, &sy, &cy);
        sincosf(fac * z, &sz, &cz);
        emb[3 + 6 * f + 0] = sx; emb[3 + 6 * f + 1] = sy; emb[3 + 6 * f + 2] = sz;
        emb[3 + 6 * f + 3] = cx; emb[3 + 6 * f + 4] = cy; emb[3 + 6 * f + 5] = cz;
    }

    float h0[64]; bias_init(h0, bb0); gemv_acc(emb, h0, wb0); relu_(h0);
    float h1[64]; bias_init(h1, bb1); gemv_acc(h0, h1, wb1); relu_(h1);
    float h2[64]; bias_init(h2, bb2); gemv_acc(h1, h2, wb2); relu_(h2);

    // skip: concat([emb(33), h2(64)]) @ wa0(97,64)
    float h3[64];
    bias_init(h3, ba0);
    gemv_acc(emb, h3, wa0);             // rows 0..32
    gemv_acc(h2,  h3, wa0 + 33 * 64);   // rows 33..96
    relu_(h3);

    float h4[64]; bias_init(h4, ba1); gemv_acc(h3, h4, wa1); relu_(h4);
    float h5[64]; bias_init(h5, ba2); gemv_acc(h4, h5, wa2); relu_(h5);
    float lat[64]; bias_init(lat, blat); gemv_acc(h5, lat, wlat);   // no relu

    // view embedding for this point's ray (3 freqs -> 21)
    const int rid = ray_id[p];
    const float vx = view[3 * rid + 0];
    const float vy = view[3 * rid + 1];
    const float vz = view[3 * rid + 2];
    float vemb[21];
    vemb[0] = vx; vemb[1] = vy; vemb[2] = vz;
#pragma unroll
    for (int f = 0; f < 3; ++f) {
        const float fac = (float)(1 << f);
        float sx, cx, sy, cy, sz, cz;
        sincosf(fac * vx, &sx, &cx);
        sincosf(fac * vy, &sy, &cy);
        sincosf(fac * vz, &sz, &cz);
        vemb[3 + 6 * f + 0] = sx; vemb[3 + 6 * f + 1] = sy; vemb[3 + 6 * f + 2] = sz;
        vemb[3 + 6 * f + 3] = cx; vemb[3 + 6 * f + 4] = cy; vemb[3 + 6 * f + 5] = cz;
    }

    // hv = relu(concat([lat(64), vemb(21)]) @ wview(85,32))
    float hv[32];
    bias_init(hv, bview);
    gemv_acc(lat,  hv, wview);            // rows 0..63
    gemv_acc(vemb, hv, wview + 64 * 32);  // rows 64..84
    relu_(hv);

    float hc[16]; bias_init(hc, bc0); gemv_acc(hv, hc, wc0); relu_(hc);
    float rr[3];  bias_init(rr, bc1); gemv_acc(hc, rr, wc1);

#pragma unroll
    for (int c = 0; c < 3; ++c)
        rgb_out[3 * p + c] = 0.5f * (tanhf(rr[c]) + 1.0f);
}

// ---------------- kernel 2: per-ray composite (one wave per ray) -----------

extern "C" __global__ void __launch_bounds__(256)
composite(const float* __restrict__ raw_density,
          const int*   __restrict__ ray_id,
          const float* __restrict__ rgb,
          float*       __restrict__ out)
{
    const int lane = threadIdx.x & 63;
    const int ray  = blockIdx.x * 4 + (threadIdx.x >> 6);

    // lower_bound(ray) and lower_bound(ray+1) in sorted ray_id
    int lo = 0, hi = NPTS;
    while (lo < hi) { const int mid = (lo + hi) >> 1; if (ray_id[mid] < ray) lo = mid + 1; else hi = mid; }
    const int start = lo;
    hi = NPTS;
    while (lo < hi) { const int mid = (lo + hi) >> 1; if (ray_id[mid] < ray + 1) lo = mid + 1; else hi = mid; }
    const int end = lo;

    float carry = 0.0f, a0 = 0.0f, a1 = 0.0f, a2 = 0.0f;

    for (int base = start; base < end; base += 64) {
        const int  idx   = base + lane;
        const bool valid = idx < end;

        float lt = 0.0f, alpha = 0.0f;
        if (valid) {
            const float xx  = raw_density[idx] + ACT_SHIFT_F;
            const float sig = fmaxf(xx, 0.0f) + log1pf(expf(-fabsf(xx)));  // softplus
            lt    = -sig * INTERVAL_F;
            alpha = 1.0f - expf(lt);
        }

        // inclusive prefix sum of lt across the wave
        float incl = lt;
#pragma unroll
        for (int d = 1; d < 64; d <<= 1) {
            const float n = __shfl_up(incl, d);
            if (lane >= d) incl += n;
        }

        const float T = expf(carry + (incl - lt));   // exclusive cumsum -> transmittance
        if (valid) {
            const float w = T * alpha;
            a0 = fmaf(w, rgb[3 * idx + 0], a0);
            a1 = fmaf(w, rgb[3 * idx + 1], a1);
            a2 = fmaf(w, rgb[3 * idx + 2], a2);
        }
        carry += __shfl(incl, 63);
    }

    // wave reduction of the three accumulators
#pragma unroll
    for (int d = 32; d > 0; d >>= 1) {
        a0 += __shfl_xor(a0, d);
        a1 += __shfl_xor(a1, d);
        a2 += __shfl_xor(a2, d);
    }

    if (lane == 0) {
        const float ainv = expf(carry);   // alphainv_last (white background)
        out[3 * ray + 0] = a0 + ainv;
        out[3 * ray + 1] = a1 + ainv;
        out[3 * ray + 2] = a2 + ainv;
    }
}

// ---------------- launch ----------------------------------------------------

extern "C" void kernel_launch(void* const* d_in, const int* in_sizes, int n_in,
                              void* d_out, int out_size, void* d_ws, size_t ws_size,
                              hipStream_t stream) {
    const float* coor        = (const float*)d_in[0];
    const float* view        = (const float*)d_in[1];
    const float* raw_density = (const float*)d_in[2];
    const int*   ray_id      = (const int*)  d_in[3];
    const float* wb0  = (const float*)d_in[4];  const float* bb0  = (const float*)d_in[5];
    const float* wb1  = (const float*)d_in[6];  const float* bb1  = (const float*)d_in[7];
    const float* wb2  = (const float*)d_in[8];  const float* bb2  = (const float*)d_in[9];
    const float* wa0  = (const float*)d_in[10]; const float* ba0  = (const float*)d_in[11];
    const float* wa1  = (const float*)d_in[12]; const float* ba1  = (const float*)d_in[13];
    const float* wa2  = (const float*)d_in[14]; const float* ba2  = (const float*)d_in[15];
    const float* wlat = (const float*)d_in[16]; const float* blat = (const float*)d_in[17];
    const float* wvw  = (const float*)d_in[18]; const float* bvw  = (const float*)d_in[19];
    const float* wc0  = (const float*)d_in[20]; const float* bc0  = (const float*)d_in[21];
    const float* wc1  = (const float*)d_in[22]; const float* bc1  = (const float*)d_in[23];

    float* rgb = (float*)d_ws;   // (P,3) f32 = 6.29 MB staging

    mlp_points<<<NPTS / 256, 256, 0, stream>>>(
        coor, view, ray_id,
        wb0, bb0, wb1, bb1, wb2, bb2,
        wa0, ba0, wa1, ba1, wa2, ba2,
        wlat, blat, wvw, bvw, wc0, bc0, wc1, bc1,
        rgb);

    composite<<<NRAYS / 4, 256, 0, stream>>>(raw_density, ray_id, rgb, (float*)d_out);
}

// Round 2
// 113.109 us; speedup vs baseline: 45.2135x; 45.2135x over previous
//
#include <hip/hip_runtime.h>
#include <math.h>

#define NPTS  524288
#define NRAYS 4096
#define ACT_SHIFT_F (-2.1972245773362196f)   // log(1/(1-0.1) - 1)
#define INTERVAL_F  0.5f

typedef _Float16 f16x8 __attribute__((ext_vector_type(8)));
typedef float    f32x4 __attribute__((ext_vector_type(4)));

// ---- padded transposed weight pool (halves offsets inside pool) ----
// layout [N][Kpad] f16, zero-padded K
#define WB0T_OFF   0        // 64 x 64   (src 33x64)
#define WB1T_OFF   4096     // 64 x 64
#define WB2T_OFF   8192     // 64 x 64
#define WA0T_OFF   12288    // 64 x 128  (src 97x64: k<33 emb, 64<=k<128 -> h2 rows 33..96)
#define WA1T_OFF   20480    // 64 x 64
#define WA2T_OFF   24576    // 64 x 64
#define WLATT_OFF  28672    // 64 x 64
#define WVIEWT_OFF 32768    // 32 x 96   (src 85x32)
#define WC0T_OFF   35840    // 16 x 32   (src 32x16)
#define POOL_HALVES 36352

#define ASTR 72   // LDS row stride (halves) for 64-wide activations (+8 pad)
#define VSTR 40   // LDS row stride for 32-wide view embedding

// ================= prep: transpose + pad weights to f16 [N][Kpad] ==========
extern "C" __global__ void __launch_bounds__(256)
prep_weights(const float* __restrict__ wb0, const float* __restrict__ wb1,
             const float* __restrict__ wb2, const float* __restrict__ wa0,
             const float* __restrict__ wa1, const float* __restrict__ wa2,
             const float* __restrict__ wlat, const float* __restrict__ wview,
             const float* __restrict__ wc0, _Float16* __restrict__ pool)
{
    const int id = blockIdx.x * 256 + threadIdx.x;
    if (id >= POOL_HALVES) return;
    int r = id;
    if (r < 4096) { int n=r>>6, k=r&63; pool[id] = (k<33)?(_Float16)wb0[k*64+n]:(_Float16)0.f; return; } r -= 4096;
    if (r < 4096) { int n=r>>6, k=r&63; pool[id] = (_Float16)wb1[k*64+n]; return; } r -= 4096;
    if (r < 4096) { int n=r>>6, k=r&63; pool[id] = (_Float16)wb2[k*64+n]; return; } r -= 4096;
    if (r < 8192) { int n=r>>7, k=r&127; float v=0.f;
                    if (k<33) v=wa0[k*64+n]; else if (k>=64) v=wa0[(k-31)*64+n];
                    pool[id]=(_Float16)v; return; } r -= 8192;
    if (r < 4096) { int n=r>>6, k=r&63; pool[id] = (_Float16)wa1[k*64+n]; return; } r -= 4096;
    if (r < 4096) { int n=r>>6, k=r&63; pool[id] = (_Float16)wa2[k*64+n]; return; } r -= 4096;
    if (r < 4096) { int n=r>>6, k=r&63; pool[id] = (_Float16)wlat[k*64+n]; return; } r -= 4096;
    if (r < 3072) { int n=r/96, k=r-96*n; float v=(k<85)?wview[k*32+n]:0.f; pool[id]=(_Float16)v; return; } r -= 3072;
    { int n=r>>5, k=r&31; pool[id] = (_Float16)wc0[k*16+n]; }
}

// ================= fused MFMA MLP ===========================================

__device__ __forceinline__ void emb_block(_Float16* row, int f, float x, float y, float z) {
    const float fac = (float)(1 << f);
    float s, c;
    _Float16* b = row + 3 + 6 * f;
    sincosf(fac * x, &s, &c); b[0] = (_Float16)s; b[3] = (_Float16)c;
    sincosf(fac * y, &s, &c); b[1] = (_Float16)s; b[4] = (_Float16)c;
    sincosf(fac * z, &s, &c); b[2] = (_Float16)s; b[5] = (_Float16)c;
}

// One fused layer: out[64 x 16*NW] = act( A[64 x 32*(KC0+KC1)] @ B + bias )
// A split into two LDS regions (skip/concat layers). B from global pool [N][Kpad].
// Layout assumptions (std CDNA): A row = lane%16, k-group = lane>>4 (8 contig k);
// same within-lane k-convention for A and B cancels. C/D: col=lane&15,
// row=(lane>>4)*4+j (HW-verified).
template<bool RELU, int KC0, int KC1, int NW>
__device__ __forceinline__ void do_layer(
    const _Float16* __restrict__ A0, int str0,
    const _Float16* __restrict__ A1, int str1,
    const _Float16* __restrict__ wT, int Kpad,
    const float* __restrict__ bias,
    _Float16* __restrict__ dst, int dstr,
    int lane, int wv)
{
    if (wv < NW) {
        const int n  = wv * 16 + (lane & 15);
        const int kg = (lane >> 4) * 8;
        const float bv = bias[n];

        f16x8 bf[KC0 + KC1];
#pragma unroll
        for (int kc = 0; kc < KC0 + KC1; ++kc)
            bf[kc] = *(const f16x8*)(wT + n * Kpad + kc * 32 + kg);

        f32x4 acc[4];
#pragma unroll
        for (int mt = 0; mt < 4; ++mt) {
            acc[mt] = (f32x4){bv, bv, bv, bv};
#pragma unroll
            for (int kc = 0; kc < KC0; ++kc) {
                f16x8 af = *(const f16x8*)(A0 + ((lane & 15) + mt * 16) * str0 + kc * 32 + kg);
                acc[mt] = __builtin_amdgcn_mfma_f32_16x16x32_f16(af, bf[kc], acc[mt], 0, 0, 0);
            }
#pragma unroll
            for (int kc = 0; kc < KC1; ++kc) {
                f16x8 af = *(const f16x8*)(A1 + ((lane & 15) + mt * 16) * str1 + kc * 32 + kg);
                acc[mt] = __builtin_amdgcn_mfma_f32_16x16x32_f16(af, bf[KC0 + kc], acc[mt], 0, 0, 0);
            }
        }
#pragma unroll
        for (int mt = 0; mt < 4; ++mt)
#pragma unroll
            for (int j = 0; j < 4; ++j) {
                float v = acc[mt][j];
                if (RELU) v = fmaxf(v, 0.0f);
                dst[(mt * 16 + (lane >> 4) * 4 + j) * dstr + n] = (_Float16)v;
            }
    }
    __syncthreads();
}

extern "C" __global__ void __launch_bounds__(256)
mlp_mfma(const float* __restrict__ coor, const float* __restrict__ view,
         const int* __restrict__ ray_id,
         const float* __restrict__ bb0, const float* __restrict__ bb1,
         const float* __restrict__ bb2, const float* __restrict__ ba0,
         const float* __restrict__ ba1, const float* __restrict__ ba2,
         const float* __restrict__ blat, const float* __restrict__ bview,
         const float* __restrict__ bc0, const float* __restrict__ wc1,
         const float* __restrict__ bc1,
         const _Float16* __restrict__ pool, _Float16* __restrict__ rgb)
{
    __shared__ __align__(16) _Float16 smem[3 * 64 * ASTR + 64 * VSTR];
    _Float16* s_emb  = smem;
    _Float16* s_act0 = smem + 64 * ASTR;
    _Float16* s_act1 = smem + 2 * 64 * ASTR;
    _Float16* s_vemb = smem + 3 * 64 * ASTR;

    const int tid  = threadIdx.x;
    const int lane = tid & 63;
    const int wv   = tid >> 6;
    const int p0   = blockIdx.x * 64;

    // ---- stage embeddings (work split across the 4 waves; g is wave-uniform)
    {
        const int p  = tid & 63;
        const int g  = tid >> 6;
        const int pt = p0 + p;
        if (g == 0) {
            const float x = coor[3*pt], y = coor[3*pt+1], z = coor[3*pt+2];
            _Float16* row = s_emb + p * ASTR;
            row[0] = (_Float16)x; row[1] = (_Float16)y; row[2] = (_Float16)z;
            emb_block(row, 0, x, y, z);
#pragma unroll
            for (int c = 33; c < 64; ++c) row[c] = (_Float16)0.f;
        } else if (g == 1) {
            const float x = coor[3*pt], y = coor[3*pt+1], z = coor[3*pt+2];
            _Float16* row = s_emb + p * ASTR;
            emb_block(row, 1, x, y, z);
            emb_block(row, 2, x, y, z);
        } else if (g == 2) {
            const float x = coor[3*pt], y = coor[3*pt+1], z = coor[3*pt+2];
            _Float16* row = s_emb + p * ASTR;
            emb_block(row, 3, x, y, z);
            emb_block(row, 4, x, y, z);
        } else {
            const int rid = ray_id[pt];
            const float x = view[3*rid], y = view[3*rid+1], z = view[3*rid+2];
            _Float16* row = s_vemb + p * VSTR;
            row[0] = (_Float16)x; row[1] = (_Float16)y; row[2] = (_Float16)z;
            emb_block(row, 0, x, y, z);
            emb_block(row, 1, x, y, z);
            emb_block(row, 2, x, y, z);
#pragma unroll
            for (int c = 21; c < 32; ++c) row[c] = (_Float16)0.f;
        }
    }
    __syncthreads();

    // ---- MLP chain (ping-pong LDS) ----
    do_layer<true , 2, 0, 4>(s_emb , ASTR, nullptr, 0, pool + WB0T_OFF , 64 , bb0 , s_act0, ASTR, lane, wv);
    do_layer<true , 2, 0, 4>(s_act0, ASTR, nullptr, 0, pool + WB1T_OFF , 64 , bb1 , s_act1, ASTR, lane, wv);
    do_layer<true , 2, 0, 4>(s_act1, ASTR, nullptr, 0, pool + WB2T_OFF , 64 , bb2 , s_act0, ASTR, lane, wv);  // h2
    do_layer<true , 2, 2, 4>(s_emb , ASTR, s_act0, ASTR, pool + WA0T_OFF , 128, ba0 , s_act1, ASTR, lane, wv); // skip
    do_layer<true , 2, 0, 4>(s_act1, ASTR, nullptr, 0, pool + WA1T_OFF , 64 , ba1 , s_act0, ASTR, lane, wv);
    do_layer<true , 2, 0, 4>(s_act0, ASTR, nullptr, 0, pool + WA2T_OFF , 64 , ba2 , s_act1, ASTR, lane, wv);
    do_layer<false, 2, 0, 4>(s_act1, ASTR, nullptr, 0, pool + WLATT_OFF, 64 , blat, s_act0, ASTR, lane, wv);  // lat
    do_layer<true , 2, 1, 2>(s_act0, ASTR, s_vemb, VSTR, pool + WVIEWT_OFF, 96, bview, s_act1, ASTR, lane, wv); // hv (cols 0..31)

    // ---- c0: hc(64x16) = relu(hv @ wc0 + bc0); f32 into s_act0 region ----
    float* hc = (float*)s_act0;
    if (wv == 0) {
        const int n  = lane & 15;
        const int kg = (lane >> 4) * 8;
        const float bv = bc0[n];
        const f16x8 bf = *(const f16x8*)(pool + WC0T_OFF + n * 32 + kg);
#pragma unroll
        for (int mt = 0; mt < 4; ++mt) {
            f32x4 acc = (f32x4){bv, bv, bv, bv};
            f16x8 af = *(const f16x8*)(s_act1 + ((lane & 15) + mt * 16) * ASTR + kg);
            acc = __builtin_amdgcn_mfma_f32_16x16x32_f16(af, bf, acc, 0, 0, 0);
#pragma unroll
            for (int j = 0; j < 4; ++j)
                hc[(mt * 16 + (lane >> 4) * 4 + j) * 16 + n] = fmaxf(acc[j], 0.0f);
        }
    }
    __syncthreads();

    // ---- c1 (16->3) + tanh squash, per point on first wave ----
    if (tid < 64) {
        float r0 = bc1[0], r1 = bc1[1], r2 = bc1[2];
#pragma unroll
        for (int j = 0; j < 16; ++j) {
            const float h = hc[tid * 16 + j];
            r0 = fmaf(h, wc1[j * 3 + 0], r0);
            r1 = fmaf(h, wc1[j * 3 + 1], r1);
            r2 = fmaf(h, wc1[j * 3 + 2], r2);
        }
        const int pt = p0 + tid;
        rgb[3 * pt + 0] = (_Float16)(0.5f * (tanhf(r0) + 1.0f));
        rgb[3 * pt + 1] = (_Float16)(0.5f * (tanhf(r1) + 1.0f));
        rgb[3 * pt + 2] = (_Float16)(0.5f * (tanhf(r2) + 1.0f));
    }
}

// ================= per-ray composite (one wave per ray) =====================
extern "C" __global__ void __launch_bounds__(256)
composite(const float* __restrict__ raw_density,
          const int*   __restrict__ ray_id,
          const _Float16* __restrict__ rgb,
          float*       __restrict__ out)
{
    const int lane = threadIdx.x & 63;
    const int ray  = blockIdx.x * 4 + (threadIdx.x >> 6);

    int lo = 0, hi = NPTS;
    while (lo < hi) { const int mid = (lo + hi) >> 1; if (ray_id[mid] < ray) lo = mid + 1; else hi = mid; }
    const int start = lo;
    hi = NPTS;
    while (lo < hi) { const int mid = (lo + hi) >> 1; if (ray_id[mid] < ray + 1) lo = mid + 1; else hi = mid; }
    const int end = lo;

    float carry = 0.0f, a0 = 0.0f, a1 = 0.0f, a2 = 0.0f;

    for (int base = start; base < end; base += 64) {
        const int  idx   = base + lane;
        const bool valid = idx < end;

        float lt = 0.0f, alpha = 0.0f;
        if (valid) {
            const float xx  = raw_density[idx] + ACT_SHIFT_F;
            const float sig = fmaxf(xx, 0.0f) + log1pf(expf(-fabsf(xx)));  // softplus
            lt    = -sig * INTERVAL_F;
            alpha = 1.0f - expf(lt);
        }

        float incl = lt;
#pragma unroll
        for (int d = 1; d < 64; d <<= 1) {
            const float n = __shfl_up(incl, d);
            if (lane >= d) incl += n;
        }

        const float T = expf(carry + (incl - lt));
        if (valid) {
            const float w = T * alpha;
            a0 = fmaf(w, (float)rgb[3 * idx + 0], a0);
            a1 = fmaf(w, (float)rgb[3 * idx + 1], a1);
            a2 = fmaf(w, (float)rgb[3 * idx + 2], a2);
        }
        carry += __shfl(incl, 63);
    }

#pragma unroll
    for (int d = 32; d > 0; d >>= 1) {
        a0 += __shfl_xor(a0, d);
        a1 += __shfl_xor(a1, d);
        a2 += __shfl_xor(a2, d);
    }

    if (lane == 0) {
        const float ainv = expf(carry);
        out[3 * ray + 0] = a0 + ainv;
        out[3 * ray + 1] = a1 + ainv;
        out[3 * ray + 2] = a2 + ainv;
    }
}

// ================= launch ===================================================
extern "C" void kernel_launch(void* const* d_in, const int* in_sizes, int n_in,
                              void* d_out, int out_size, void* d_ws, size_t ws_size,
                              hipStream_t stream) {
    const float* coor        = (const float*)d_in[0];
    const float* view        = (const float*)d_in[1];
    const float* raw_density = (const float*)d_in[2];
    const int*   ray_id      = (const int*)  d_in[3];
    const float* wb0  = (const float*)d_in[4];  const float* bb0  = (const float*)d_in[5];
    const float* wb1  = (const float*)d_in[6];  const float* bb1  = (const float*)d_in[7];
    const float* wb2  = (const float*)d_in[8];  const float* bb2  = (const float*)d_in[9];
    const float* wa0  = (const float*)d_in[10]; const float* ba0  = (const float*)d_in[11];
    const float* wa1  = (const float*)d_in[12]; const float* ba1  = (const float*)d_in[13];
    const float* wa2  = (const float*)d_in[14]; const float* ba2  = (const float*)d_in[15];
    const float* wlat = (const float*)d_in[16]; const float* blat = (const float*)d_in[17];
    const float* wvw  = (const float*)d_in[18]; const float* bvw  = (const float*)d_in[19];
    const float* wc0  = (const float*)d_in[20]; const float* bc0  = (const float*)d_in[21];
    const float* wc1  = (const float*)d_in[22]; const float* bc1  = (const float*)d_in[23];

    _Float16* rgb  = (_Float16*)d_ws;                                   // P*3 f16 = 3.15 MB
    _Float16* pool = (_Float16*)((char*)d_ws + (size_t)NPTS * 3 * 2);   // 72.7 KB

    prep_weights<<<(POOL_HALVES + 255) / 256, 256, 0, stream>>>(
        wb0, wb1, wb2, wa0, wa1, wa2, wlat, wvw, wc0, pool);

    mlp_mfma<<<NPTS / 64, 256, 0, stream>>>(
        coor, view, ray_id,
        bb0, bb1, bb2, ba0, ba1, ba2, blat, bvw, bc0, wc1, bc1,
        pool, rgb);

    composite<<<NRAYS / 4, 256, 0, stream>>>(raw_density, ray_id, rgb, (float*)d_out);
}